// Round 6
// baseline (405.018 us; speedup 1.0000x reference)
//
#include <hip/hip_runtime.h>
#include <hip/hip_fp16.h>

typedef float    f32x4 __attribute__((ext_vector_type(4)));
typedef _Float16 f16x8 __attribute__((ext_vector_type(8)));
typedef _Float16 f16x4 __attribute__((ext_vector_type(4)));

#define NBB   512
#define HT_ST 520   // f16 row stride (512+8): 16B-aligned rows

__device__ __forceinline__ int binidx(float heading, float bearing) {
    float sh = heading + 15.0f; sh = (sh >= 360.0f) ? sh - 360.0f : sh;
    float sb = bearing + 15.0f; sb = (sb >= 360.0f) ? sb - 360.0f : sb;
    int ih = (int)floorf(sh * (1.0f / 30.0f)); ih = min(max(ih, 0), 11);
    int ib = (int)floorf(sb * (1.0f / 30.0f)); ib = min(max(ib, 0), 11);
    return ih * 12 + ib;
}

__global__ __launch_bounds__(512, 4) void spatial_attn_kernel(
    const float* __restrict__ hid,
    const float* __restrict__ dist,
    const float* __restrict__ bear,
    const float* __restrict__ head,
    const float* __restrict__ mask,
    const float* __restrict__ dom,
    float* __restrict__ out)
{
    __shared__ __align__(16) _Float16 sHT[64][HT_ST];   // hidden^T f16 (~66.6 KB)
    __shared__ __align__(16) float    sMask[NBB];
    __shared__ __align__(16) float    sDom[144];

    const int tid  = threadIdx.x;
    const int lane = tid & 63;
    const int wid  = tid >> 6;      // 0..7
    const int l16  = lane & 15;
    const int kg   = lane >> 4;     // 0..3

    // XCD-aware mapping: 4 row-blocks of one batch share an XCD (hid L2 reuse)
    const int g    = blockIdx.x;
    const int xcd  = g & 7;
    const int jj8  = g >> 3;
    const int b    = xcd * 16 + (jj8 >> 2);
    const int i0blk = (jj8 & 3) << 7;

    if (tid < NBB) sMask[tid] = mask[b * NBB + tid];
    if (tid < 144) sDom[tid]  = dom[tid];

    // ---- stage hidden^T (f16) into LDS; copy our 128-row slice to out[:,64:128] ----
    {
        const int d4 = tid & 15;
        const int jg = tid >> 4;
        const f32x4* hid4 = (const f32x4*)(hid + (size_t)b * NBB * 64);
        #pragma unroll
        for (int it = 0; it < 4; ++it) {
            const int j0 = 4 * jg + 128 * it;
            f32x4 v0 = hid4[(j0 + 0) * 16 + d4];
            f32x4 v1 = hid4[(j0 + 1) * 16 + d4];
            f32x4 v2 = hid4[(j0 + 2) * 16 + d4];
            f32x4 v3 = hid4[(j0 + 3) * 16 + d4];
            if (j0 >= i0blk && j0 < i0blk + 128) {
                *(f32x4*)(out + (size_t)(b * NBB + j0 + 0) * 128 + 64 + 4 * d4) = v0;
                *(f32x4*)(out + (size_t)(b * NBB + j0 + 1) * 128 + 64 + 4 * d4) = v1;
                *(f32x4*)(out + (size_t)(b * NBB + j0 + 2) * 128 + 64 + 4 * d4) = v2;
                *(f32x4*)(out + (size_t)(b * NBB + j0 + 3) * 128 + 64 + 4 * d4) = v3;
            }
            #pragma unroll
            for (int c = 0; c < 4; ++c) {
                f16x4 hv;
                hv[0] = (_Float16)v0[c]; hv[1] = (_Float16)v1[c];
                hv[2] = (_Float16)v2[c]; hv[3] = (_Float16)v3[c];
                *(f16x4*)&sHT[4 * d4 + c][j0] = hv;
            }
        }
    }
    __syncthreads();   // the ONLY barrier

    const float domc = sDom[0];
    int okc = (sDom[lane] == domc) && (sDom[lane + 64] == domc);
    if (lane < 16) okc = okc && (sDom[lane + 128] == domc);
    const bool uni = __all(okc);

    // lane-group (l16, kg=0..3) owns row i; its 128 cols are 8kg+32t, t=0..15
    const int    i     = i0blk + wid * 16 + l16;
    const float  mi    = sMask[i];
    const size_t gri   = (size_t)b * NBB + i;
    const float* dbase = dist + gri * NBB + 8 * kg;
    const int    tdiag = i >> 5;

    f32x4 acc0 = {0.f,0.f,0.f,0.f}, acc1 = acc0, acc2 = acc0, acc3 = acc0;
    float sum;

    if (uni) {
        // ---- Phase A: stream dist from HBM, masked row-max only (no W storage) ----
        f32x4 mxA = acc0, mxB = acc0;
        #pragma unroll
        for (int t = 0; t < 16; ++t) {
            const f32x4 d0 = *(const f32x4*)(dbase + 32 * t);
            const f32x4 d1 = *(const f32x4*)(dbase + 32 * t + 4);
            const int kbase = 32 * t + 8 * kg;
            const f32x4 m0 = *(const f32x4*)(sMask + kbase);
            const f32x4 m1 = *(const f32x4*)(sMask + kbase + 4);
            f32x4 wA, wB;
            #pragma unroll
            for (int q = 0; q < 4; ++q) {
                wA[q] = fmaxf(domc - d0[q], 0.0f) * m0[q];
                wB[q] = fmaxf(domc - d1[q], 0.0f) * m1[q];
            }
            if (t == tdiag) {
                #pragma unroll
                for (int q = 0; q < 4; ++q) {
                    if (kbase + q     == i) wA[q] = 0.0f;
                    if (kbase + 4 + q == i) wB[q] = 0.0f;
                }
            }
            #pragma unroll
            for (int q = 0; q < 4; ++q) {
                mxA[q] = fmaxf(mxA[q], wA[q]);
                mxB[q] = fmaxf(mxB[q], wB[q]);
            }
        }
        float mx = fmaxf(fmaxf(fmaxf(mxA[0], mxA[1]), fmaxf(mxA[2], mxA[3])),
                         fmaxf(fmaxf(mxB[0], mxB[1]), fmaxf(mxB[2], mxB[3])));
        mx = fmaxf(mx, __shfl_xor(mx, 16));
        mx = fmaxf(mx, __shfl_xor(mx, 32));
        const float rinv = 1.0f / (mx + 1e-14f);

        // ---- Phase B: re-stream dist (L2/L3-hot), recompute -> exp -> MFMA immediately ----
        f32x4 sA = acc0, sB = acc0;
        #pragma unroll
        for (int t = 0; t < 16; ++t) {
            const f32x4 d0 = *(const f32x4*)(dbase + 32 * t);
            const f32x4 d1 = *(const f32x4*)(dbase + 32 * t + 4);
            const int kbase = 32 * t + 8 * kg;
            const f32x4 m0 = *(const f32x4*)(sMask + kbase);
            const f32x4 m1 = *(const f32x4*)(sMask + kbase + 4);
            f32x4 wA, wB;
            #pragma unroll
            for (int q = 0; q < 4; ++q) {
                wA[q] = fmaxf(domc - d0[q], 0.0f) * m0[q];
                wB[q] = fmaxf(domc - d1[q], 0.0f) * m1[q];
            }
            if (t == tdiag) {
                #pragma unroll
                for (int q = 0; q < 4; ++q) {
                    if (kbase + q     == i) wA[q] = 0.0f;
                    if (kbase + 4 + q == i) wB[q] = 0.0f;
                }
            }
            f16x8 h;
            #pragma unroll
            for (int q = 0; q < 4; ++q) {
                float wn = wA[q] * rinv;
                float e  = (wn != 0.0f) ? __expf(wn) : 0.0f;
                sA[q] += e;  h[q] = (_Float16)e;
                wn = wB[q] * rinv;
                e  = (wn != 0.0f) ? __expf(wn) : 0.0f;
                sB[q] += e;  h[4 + q] = (_Float16)e;
            }
            acc0 = __builtin_amdgcn_mfma_f32_16x16x32_f16(*(const f16x8*)&sHT[     l16][kbase], h, acc0, 0, 0, 0);
            acc1 = __builtin_amdgcn_mfma_f32_16x16x32_f16(*(const f16x8*)&sHT[16 + l16][kbase], h, acc1, 0, 0, 0);
            acc2 = __builtin_amdgcn_mfma_f32_16x16x32_f16(*(const f16x8*)&sHT[32 + l16][kbase], h, acc2, 0, 0, 0);
            acc3 = __builtin_amdgcn_mfma_f32_16x16x32_f16(*(const f16x8*)&sHT[48 + l16][kbase], h, acc3, 0, 0, 0);
        }
        sum = sA[0]+sA[1]+sA[2]+sA[3] + sB[0]+sB[1]+sB[2]+sB[3];
    } else {
        // ---- general path (correctness only): same two-phase recompute with bin gather ----
        const float* bbase = bear + gri * NBB + 8 * kg;
        const float* hbase = head + gri * NBB + 8 * kg;
        float mx = 0.0f;
        #pragma unroll 2
        for (int t = 0; t < 16; ++t) {
            const f32x4 d0 = *(const f32x4*)(dbase + 32 * t);
            const f32x4 d1 = *(const f32x4*)(dbase + 32 * t + 4);
            const f32x4 b0 = *(const f32x4*)(bbase + 32 * t);
            const f32x4 b1 = *(const f32x4*)(bbase + 32 * t + 4);
            const f32x4 h0 = *(const f32x4*)(hbase + 32 * t);
            const f32x4 h1 = *(const f32x4*)(hbase + 32 * t + 4);
            const int kbase = 32 * t + 8 * kg;
            const f32x4 m0 = *(const f32x4*)(sMask + kbase);
            const f32x4 m1 = *(const f32x4*)(sMask + kbase + 4);
            #pragma unroll
            for (int q = 0; q < 4; ++q) {
                float wA = fmaxf(sDom[binidx(h0[q], b0[q])] - d0[q], 0.0f) * m0[q];
                float wB = fmaxf(sDom[binidx(h1[q], b1[q])] - d1[q], 0.0f) * m1[q];
                if (kbase + q     == i) wA = 0.0f;
                if (kbase + 4 + q == i) wB = 0.0f;
                mx = fmaxf(mx, fmaxf(wA, wB));
            }
        }
        mx = fmaxf(mx, __shfl_xor(mx, 16));
        mx = fmaxf(mx, __shfl_xor(mx, 32));
        const float rinv = 1.0f / (mx + 1e-14f);
        float s = 0.0f;
        #pragma unroll 2
        for (int t = 0; t < 16; ++t) {
            const f32x4 d0 = *(const f32x4*)(dbase + 32 * t);
            const f32x4 d1 = *(const f32x4*)(dbase + 32 * t + 4);
            const f32x4 b0 = *(const f32x4*)(bbase + 32 * t);
            const f32x4 b1 = *(const f32x4*)(bbase + 32 * t + 4);
            const f32x4 h0 = *(const f32x4*)(hbase + 32 * t);
            const f32x4 h1 = *(const f32x4*)(hbase + 32 * t + 4);
            const int kbase = 32 * t + 8 * kg;
            const f32x4 m0 = *(const f32x4*)(sMask + kbase);
            const f32x4 m1 = *(const f32x4*)(sMask + kbase + 4);
            f16x8 h;
            #pragma unroll
            for (int q = 0; q < 4; ++q) {
                float wA = fmaxf(sDom[binidx(h0[q], b0[q])] - d0[q], 0.0f) * m0[q];
                float wB = fmaxf(sDom[binidx(h1[q], b1[q])] - d1[q], 0.0f) * m1[q];
                if (kbase + q     == i) wA = 0.0f;
                if (kbase + 4 + q == i) wB = 0.0f;
                float wn = wA * rinv;
                float e  = (wn != 0.0f) ? __expf(wn) : 0.0f;
                s += e;  h[q] = (_Float16)e;
                wn = wB * rinv;
                e  = (wn != 0.0f) ? __expf(wn) : 0.0f;
                s += e;  h[4 + q] = (_Float16)e;
            }
            acc0 = __builtin_amdgcn_mfma_f32_16x16x32_f16(*(const f16x8*)&sHT[     l16][kbase], h, acc0, 0, 0, 0);
            acc1 = __builtin_amdgcn_mfma_f32_16x16x32_f16(*(const f16x8*)&sHT[16 + l16][kbase], h, acc1, 0, 0, 0);
            acc2 = __builtin_amdgcn_mfma_f32_16x16x32_f16(*(const f16x8*)&sHT[32 + l16][kbase], h, acc2, 0, 0, 0);
            acc3 = __builtin_amdgcn_mfma_f32_16x16x32_f16(*(const f16x8*)&sHT[48 + l16][kbase], h, acc3, 0, 0, 0);
        }
        sum = s;
    }

    sum += __shfl_xor(sum, 16);
    sum += __shfl_xor(sum, 32);
    const float gsc = (sum != 0.0f) ? (mi / (sum + 1e-14f)) : 0.0f;

    // D(m,n): lane = n + 16*kg', reg r -> m = 4*kg' + r; n = l16 = own row (layout verified R1)
    float* orow = out + gri * 128 + 4 * kg;
    *(f32x4*)(orow +  0) = acc0 * gsc;
    *(f32x4*)(orow + 16) = acc1 * gsc;
    *(f32x4*)(orow + 32) = acc2 * gsc;
    *(f32x4*)(orow + 48) = acc3 * gsc;
}

extern "C" void kernel_launch(void* const* d_in, const int* in_sizes, int n_in,
                              void* d_out, int out_size, void* d_ws, size_t ws_size,
                              hipStream_t stream) {
    (void)in_sizes; (void)n_in; (void)d_ws; (void)ws_size; (void)out_size;
    const float* hid  = (const float*)d_in[0];
    const float* dist = (const float*)d_in[1];
    const float* bear = (const float*)d_in[2];
    const float* head = (const float*)d_in[3];
    const float* mask = (const float*)d_in[4];
    const float* dom  = (const float*)d_in[5];
    float* out = (float*)d_out;
    hipLaunchKernelGGL(spatial_attn_kernel, dim3(512), dim3(512), 0, stream,
                       hid, dist, bear, head, mask, dom, out);
}

// Round 7
// 333.927 us; speedup vs baseline: 1.2129x; 1.2129x over previous
//
#include <hip/hip_runtime.h>
#include <hip/hip_fp16.h>

typedef float    f32x4 __attribute__((ext_vector_type(4)));
typedef _Float16 f16x8 __attribute__((ext_vector_type(8)));
typedef _Float16 f16x4 __attribute__((ext_vector_type(4)));

#define NBB   512
#define HT_ST 520   // f16 row stride (512+8): 16B-aligned rows

__device__ __forceinline__ int binidx(float heading, float bearing) {
    float sh = heading + 15.0f; sh = (sh >= 360.0f) ? sh - 360.0f : sh;
    float sb = bearing + 15.0f; sb = (sb >= 360.0f) ? sb - 360.0f : sb;
    int ih = (int)floorf(sh * (1.0f / 30.0f)); ih = min(max(ih, 0), 11);
    int ib = (int)floorf(sb * (1.0f / 30.0f)); ib = min(max(ib, 0), 11);
    return ih * 12 + ib;
}

// launch_bounds(512, 2): under "min waves/EU" semantics -> VGPR cap 256;
// under CUDA "min blocks/CU" semantics -> 16 waves/CU = 4/EU -> cap 128.
// Either way >= 128, vs the 64-VGPR cap that caused v2/v3's scratch spills.
__global__ __launch_bounds__(512, 2) void spatial_attn_kernel(
    const float* __restrict__ hid,
    const float* __restrict__ dist,
    const float* __restrict__ bear,
    const float* __restrict__ head,
    const float* __restrict__ mask,
    const float* __restrict__ dom,
    float* __restrict__ out)
{
    __shared__ __align__(16) _Float16 sHT[64][HT_ST];   // hidden^T f16 (~66.6 KB)
    __shared__ __align__(16) float    sMask[NBB];
    __shared__ __align__(16) float    sDom[144];

    const int tid  = threadIdx.x;
    const int lane = tid & 63;
    const int wid  = tid >> 6;      // 0..7
    const int l16  = lane & 15;
    const int kg   = lane >> 4;     // 0..3

    // XCD-aware mapping: 4 row-blocks of one batch share an XCD (hid L2 reuse)
    const int g    = blockIdx.x;
    const int xcd  = g & 7;
    const int jj8  = g >> 3;
    const int b    = xcd * 16 + (jj8 >> 2);
    const int i0blk = (jj8 & 3) << 7;

    if (tid < NBB) sMask[tid] = mask[b * NBB + tid];
    if (tid < 144) sDom[tid]  = dom[tid];

    // ---- stage hidden^T (f16) into LDS; copy our 128-row slice to out[:,64:128] ----
    {
        const int d4 = tid & 15;
        const int jg = tid >> 4;
        const f32x4* hid4 = (const f32x4*)(hid + (size_t)b * NBB * 64);
        #pragma unroll
        for (int it = 0; it < 4; ++it) {
            const int j0 = 4 * jg + 128 * it;
            f32x4 v0 = hid4[(j0 + 0) * 16 + d4];
            f32x4 v1 = hid4[(j0 + 1) * 16 + d4];
            f32x4 v2 = hid4[(j0 + 2) * 16 + d4];
            f32x4 v3 = hid4[(j0 + 3) * 16 + d4];
            if (j0 >= i0blk && j0 < i0blk + 128) {
                *(f32x4*)(out + (size_t)(b * NBB + j0 + 0) * 128 + 64 + 4 * d4) = v0;
                *(f32x4*)(out + (size_t)(b * NBB + j0 + 1) * 128 + 64 + 4 * d4) = v1;
                *(f32x4*)(out + (size_t)(b * NBB + j0 + 2) * 128 + 64 + 4 * d4) = v2;
                *(f32x4*)(out + (size_t)(b * NBB + j0 + 3) * 128 + 64 + 4 * d4) = v3;
            }
            #pragma unroll
            for (int c = 0; c < 4; ++c) {
                f16x4 hv;
                hv[0] = (_Float16)v0[c]; hv[1] = (_Float16)v1[c];
                hv[2] = (_Float16)v2[c]; hv[3] = (_Float16)v3[c];
                *(f16x4*)&sHT[4 * d4 + c][j0] = hv;
            }
        }
    }
    __syncthreads();   // the ONLY barrier

    const float domc = sDom[0];
    int okc = (sDom[lane] == domc) && (sDom[lane + 64] == domc);
    if (lane < 16) okc = okc && (sDom[lane + 128] == domc);
    const bool uni = __all(okc);

    // lane-group (l16, kg=0..3) owns row i; its 128 cols are 8kg+32t, t=0..15
    const int    i     = i0blk + wid * 16 + l16;
    const float  mi    = sMask[i];
    const size_t gri   = (size_t)b * NBB + i;
    const float* dbase = dist + gri * NBB + 8 * kg;
    const int    tdiag = i >> 5;

    f32x4 acc0 = {0.f,0.f,0.f,0.f}, acc1 = acc0, acc2 = acc0, acc3 = acc0;
    float sum;

    if (uni) {
        // ---- Phase A: stream dist from HBM, masked row-max only (no W storage) ----
        f32x4 mxA = acc0, mxB = acc0;
        #pragma unroll 4
        for (int t = 0; t < 16; ++t) {
            const f32x4 d0 = *(const f32x4*)(dbase + 32 * t);
            const f32x4 d1 = *(const f32x4*)(dbase + 32 * t + 4);
            const int kbase = 32 * t + 8 * kg;
            const f32x4 m0 = *(const f32x4*)(sMask + kbase);
            const f32x4 m1 = *(const f32x4*)(sMask + kbase + 4);
            f32x4 wA, wB;
            #pragma unroll
            for (int q = 0; q < 4; ++q) {
                wA[q] = fmaxf(domc - d0[q], 0.0f) * m0[q];
                wB[q] = fmaxf(domc - d1[q], 0.0f) * m1[q];
            }
            if (t == tdiag) {
                #pragma unroll
                for (int q = 0; q < 4; ++q) {
                    if (kbase + q     == i) wA[q] = 0.0f;
                    if (kbase + 4 + q == i) wB[q] = 0.0f;
                }
            }
            #pragma unroll
            for (int q = 0; q < 4; ++q) {
                mxA[q] = fmaxf(mxA[q], wA[q]);
                mxB[q] = fmaxf(mxB[q], wB[q]);
            }
        }
        float mx = fmaxf(fmaxf(fmaxf(mxA[0], mxA[1]), fmaxf(mxA[2], mxA[3])),
                         fmaxf(fmaxf(mxB[0], mxB[1]), fmaxf(mxB[2], mxB[3])));
        mx = fmaxf(mx, __shfl_xor(mx, 16));
        mx = fmaxf(mx, __shfl_xor(mx, 32));
        const float rinv = 1.0f / (mx + 1e-14f);

        // ---- Phase B: re-stream dist (L2/L3-hot), recompute -> exp -> MFMA immediately ----
        f32x4 sA = acc0, sB = acc0;
        #pragma unroll 4
        for (int t = 0; t < 16; ++t) {
            const f32x4 d0 = *(const f32x4*)(dbase + 32 * t);
            const f32x4 d1 = *(const f32x4*)(dbase + 32 * t + 4);
            const int kbase = 32 * t + 8 * kg;
            const f32x4 m0 = *(const f32x4*)(sMask + kbase);
            const f32x4 m1 = *(const f32x4*)(sMask + kbase + 4);
            f32x4 wA, wB;
            #pragma unroll
            for (int q = 0; q < 4; ++q) {
                wA[q] = fmaxf(domc - d0[q], 0.0f) * m0[q];
                wB[q] = fmaxf(domc - d1[q], 0.0f) * m1[q];
            }
            if (t == tdiag) {
                #pragma unroll
                for (int q = 0; q < 4; ++q) {
                    if (kbase + q     == i) wA[q] = 0.0f;
                    if (kbase + 4 + q == i) wB[q] = 0.0f;
                }
            }
            f16x8 h;
            #pragma unroll
            for (int q = 0; q < 4; ++q) {
                float wn = wA[q] * rinv;
                float e  = (wn != 0.0f) ? __expf(wn) : 0.0f;
                sA[q] += e;  h[q] = (_Float16)e;
                wn = wB[q] * rinv;
                e  = (wn != 0.0f) ? __expf(wn) : 0.0f;
                sB[q] += e;  h[4 + q] = (_Float16)e;
            }
            acc0 = __builtin_amdgcn_mfma_f32_16x16x32_f16(*(const f16x8*)&sHT[     l16][kbase], h, acc0, 0, 0, 0);
            acc1 = __builtin_amdgcn_mfma_f32_16x16x32_f16(*(const f16x8*)&sHT[16 + l16][kbase], h, acc1, 0, 0, 0);
            acc2 = __builtin_amdgcn_mfma_f32_16x16x32_f16(*(const f16x8*)&sHT[32 + l16][kbase], h, acc2, 0, 0, 0);
            acc3 = __builtin_amdgcn_mfma_f32_16x16x32_f16(*(const f16x8*)&sHT[48 + l16][kbase], h, acc3, 0, 0, 0);
        }
        sum = sA[0]+sA[1]+sA[2]+sA[3] + sB[0]+sB[1]+sB[2]+sB[3];
    } else {
        // ---- general path (correctness only): same two-phase recompute with bin gather ----
        const float* bbase = bear + gri * NBB + 8 * kg;
        const float* hbase = head + gri * NBB + 8 * kg;
        float mx = 0.0f;
        #pragma unroll 1
        for (int t = 0; t < 16; ++t) {
            const f32x4 d0 = *(const f32x4*)(dbase + 32 * t);
            const f32x4 d1 = *(const f32x4*)(dbase + 32 * t + 4);
            const f32x4 b0 = *(const f32x4*)(bbase + 32 * t);
            const f32x4 b1 = *(const f32x4*)(bbase + 32 * t + 4);
            const f32x4 h0 = *(const f32x4*)(hbase + 32 * t);
            const f32x4 h1 = *(const f32x4*)(hbase + 32 * t + 4);
            const int kbase = 32 * t + 8 * kg;
            const f32x4 m0 = *(const f32x4*)(sMask + kbase);
            const f32x4 m1 = *(const f32x4*)(sMask + kbase + 4);
            #pragma unroll
            for (int q = 0; q < 4; ++q) {
                float wA = fmaxf(sDom[binidx(h0[q], b0[q])] - d0[q], 0.0f) * m0[q];
                float wB = fmaxf(sDom[binidx(h1[q], b1[q])] - d1[q], 0.0f) * m1[q];
                if (kbase + q     == i) wA = 0.0f;
                if (kbase + 4 + q == i) wB = 0.0f;
                mx = fmaxf(mx, fmaxf(wA, wB));
            }
        }
        mx = fmaxf(mx, __shfl_xor(mx, 16));
        mx = fmaxf(mx, __shfl_xor(mx, 32));
        const float rinv = 1.0f / (mx + 1e-14f);
        float s = 0.0f;
        #pragma unroll 1
        for (int t = 0; t < 16; ++t) {
            const f32x4 d0 = *(const f32x4*)(dbase + 32 * t);
            const f32x4 d1 = *(const f32x4*)(dbase + 32 * t + 4);
            const f32x4 b0 = *(const f32x4*)(bbase + 32 * t);
            const f32x4 b1 = *(const f32x4*)(bbase + 32 * t + 4);
            const f32x4 h0 = *(const f32x4*)(hbase + 32 * t);
            const f32x4 h1 = *(const f32x4*)(hbase + 32 * t + 4);
            const int kbase = 32 * t + 8 * kg;
            const f32x4 m0 = *(const f32x4*)(sMask + kbase);
            const f32x4 m1 = *(const f32x4*)(sMask + kbase + 4);
            f16x8 h;
            #pragma unroll
            for (int q = 0; q < 4; ++q) {
                float wA = fmaxf(sDom[binidx(h0[q], b0[q])] - d0[q], 0.0f) * m0[q];
                float wB = fmaxf(sDom[binidx(h1[q], b1[q])] - d1[q], 0.0f) * m1[q];
                if (kbase + q     == i) wA = 0.0f;
                if (kbase + 4 + q == i) wB = 0.0f;
                float wn = wA * rinv;
                float e  = (wn != 0.0f) ? __expf(wn) : 0.0f;
                s += e;  h[q] = (_Float16)e;
                wn = wB * rinv;
                e  = (wn != 0.0f) ? __expf(wn) : 0.0f;
                s += e;  h[4 + q] = (_Float16)e;
            }
            acc0 = __builtin_amdgcn_mfma_f32_16x16x32_f16(*(const f16x8*)&sHT[     l16][kbase], h, acc0, 0, 0, 0);
            acc1 = __builtin_amdgcn_mfma_f32_16x16x32_f16(*(const f16x8*)&sHT[16 + l16][kbase], h, acc1, 0, 0, 0);
            acc2 = __builtin_amdgcn_mfma_f32_16x16x32_f16(*(const f16x8*)&sHT[32 + l16][kbase], h, acc2, 0, 0, 0);
            acc3 = __builtin_amdgcn_mfma_f32_16x16x32_f16(*(const f16x8*)&sHT[48 + l16][kbase], h, acc3, 0, 0, 0);
        }
        sum = s;
    }

    sum += __shfl_xor(sum, 16);
    sum += __shfl_xor(sum, 32);
    const float gsc = (sum != 0.0f) ? (mi / (sum + 1e-14f)) : 0.0f;

    // D(m,n): lane = n + 16*kg', reg r -> m = 4*kg' + r; n = l16 = own row (layout verified R1)
    float* orow = out + gri * 128 + 4 * kg;
    *(f32x4*)(orow +  0) = acc0 * gsc;
    *(f32x4*)(orow + 16) = acc1 * gsc;
    *(f32x4*)(orow + 32) = acc2 * gsc;
    *(f32x4*)(orow + 48) = acc3 * gsc;
}

extern "C" void kernel_launch(void* const* d_in, const int* in_sizes, int n_in,
                              void* d_out, int out_size, void* d_ws, size_t ws_size,
                              hipStream_t stream) {
    (void)in_sizes; (void)n_in; (void)d_ws; (void)ws_size; (void)out_size;
    const float* hid  = (const float*)d_in[0];
    const float* dist = (const float*)d_in[1];
    const float* bear = (const float*)d_in[2];
    const float* head = (const float*)d_in[3];
    const float* mask = (const float*)d_in[4];
    const float* dom  = (const float*)d_in[5];
    float* out = (float*)d_out;
    hipLaunchKernelGGL(spatial_attn_kernel, dim3(512), dim3(512), 0, stream,
                       hid, dist, bear, head, mask, dom, out);
}